// Round 2
// baseline (511.306 us; speedup 1.0000x reference)
//
#include <hip/hip_runtime.h>
#include <math.h>

// Problem constants (from reference)
#define BSZ   128
#define SSZ   1024
#define HSZ   768
#define MAXV  25
#define SLEVI (SSZ - 2 * MAXV)   // 974

// -----------------------------------------------------------------------------
// Fully fused TokenPooler: one block per batch (128 blocks x 256 threads).
//
// Algebraic note: within a batch, dot(subject_hidden,align_w[:H]) + align_b is
// the SAME additive constant for every masked token, so it cancels exactly in
// softmax(x - max).  subject_hidden / align_b / align_w[:H] are never read.
//
// Phases (all in one kernel, pooled lives in LDS -> no d_ws, no 2nd launch):
//   1. scores sc[t] = dot(hidden[b,s_t,:], align_w[H:]),  t < 2*v  (<=48)
//   2. softmax over sc on wave 0 (lane-parallel, <=48 active lanes)
//   3. pooled[h]    = sum_t wts[t]*hidden[b,s_t,h]   (float4, coalesced)
//   4. out[b,i]     = tanh(dot(out_w[i,:], pooled) + out_b[i])
//      out_w is 2.36 MB -> L2-resident across all 128 blocks.
// -----------------------------------------------------------------------------
__global__ __launch_bounds__(256) void fused_pooler_kernel(
    const float* __restrict__ hidden,      // [B,S,H]
    const int*   __restrict__ verb_count,  // [B]
    const float* __restrict__ align_w,     // [2H]
    const float* __restrict__ out_w,       // [H,H] row-major
    const float* __restrict__ out_b,       // [H]
    float*       __restrict__ out)         // [B,H]
{
    const int b    = blockIdx.x;
    const int tid  = threadIdx.x;
    const int lane = tid & 63;
    const int wave = tid >> 6;

    int v = verb_count[b];
    if (v < 0)    v = 0;
    if (v > MAXV) v = MAXV;
    const int nt = 2 * v;                  // masked tokens (<= 48)

    __shared__ float sc    [2 * MAXV];
    __shared__ float wts   [2 * MAXV];
    __shared__ float pooled[HSZ];          // 3 KB

    const float* __restrict__ w2 = align_w + HSZ;

    // ---- Phase 1: scores (wave w handles tokens t = w, w+4, ...) ----------
    for (int t = wave; t < nt; t += 4) {
        const int s = (t < v) ? (SLEVI + t) : (SLEVI + MAXV + (t - v));
        const float* __restrict__ row = hidden + ((size_t)b * SSZ + s) * HSZ;
        float acc = 0.0f;
#pragma unroll
        for (int k = 0; k < 3; ++k) {                 // 64 lanes * 3 float4 = 768
            const int idx = 4 * lane + 256 * k;
            const float4 r = *(const float4*)(row + idx);
            const float4 w = *(const float4*)(w2  + idx);
            acc = fmaf(r.x, w.x, acc);
            acc = fmaf(r.y, w.y, acc);
            acc = fmaf(r.z, w.z, acc);
            acc = fmaf(r.w, w.w, acc);
        }
#pragma unroll
        for (int off = 32; off > 0; off >>= 1) acc += __shfl_down(acc, off);
        if (lane == 0) sc[t] = acc;
    }
    __syncthreads();

    // ---- Phase 2: softmax on wave 0 (lanes 0..nt-1 active) -----------------
    if (wave == 0) {
        float x = (lane < nt) ? sc[lane] : -INFINITY;
        float m = x;
#pragma unroll
        for (int off = 32; off > 0; off >>= 1) m = fmaxf(m, __shfl_xor(m, off));
        const float e = (lane < nt) ? expf(x - m) : 0.0f;
        float d = e;
#pragma unroll
        for (int off = 32; off > 0; off >>= 1) d += __shfl_xor(d, off);
        if (lane < nt) wts[lane] = e / d;   // d >= 1 when nt > 0 (max term = 1)
    }
    __syncthreads();

    // ---- Phase 3: pooled (192 threads x float4, coalesced; waves 0-2) ------
    if (tid < HSZ / 4) {                    // 192 threads
        float4 acc = make_float4(0.f, 0.f, 0.f, 0.f);
        const float* __restrict__ base = hidden + ((size_t)b * SSZ) * HSZ + 4 * tid;
        for (int t = 0; t < nt; ++t) {
            const int s = (t < v) ? (SLEVI + t) : (SLEVI + MAXV + (t - v));
            const float w = wts[t];         // LDS broadcast
            const float4 r = *(const float4*)(base + (size_t)s * HSZ);
            acc.x = fmaf(w, r.x, acc.x);
            acc.y = fmaf(w, r.y, acc.y);
            acc.z = fmaf(w, r.z, acc.z);
            acc.w = fmaf(w, r.w, acc.w);
        }
        *(float4*)(pooled + 4 * tid) = acc;
    }
    __syncthreads();

    // ---- Phase 4: out[b,i] = tanh(dot(out_w[i,:], pooled) + out_b[i]) ------
    // Each thread owns features tid, tid+256, tid+512.  out_w rows are a
    // 3KB-strided gather across lanes, but out_w (2.36 MB) is L2-resident
    // (shared by all 128 blocks) and each 64B line is reused over 4 j-iters.
    {
        const float* __restrict__ wr0 = out_w + (size_t)(tid      ) * HSZ;
        const float* __restrict__ wr1 = out_w + (size_t)(tid + 256) * HSZ;
        const float* __restrict__ wr2 = out_w + (size_t)(tid + 512) * HSZ;
        float a0 = 0.f, a1 = 0.f, a2 = 0.f;
#pragma unroll 4
        for (int j = 0; j < HSZ; j += 4) {
            const float4 p  = *(const float4*)(pooled + j);   // LDS, uniform
            const float4 x0 = *(const float4*)(wr0 + j);
            const float4 x1 = *(const float4*)(wr1 + j);
            const float4 x2 = *(const float4*)(wr2 + j);
            a0 = fmaf(x0.x, p.x, a0); a0 = fmaf(x0.y, p.y, a0);
            a0 = fmaf(x0.z, p.z, a0); a0 = fmaf(x0.w, p.w, a0);
            a1 = fmaf(x1.x, p.x, a1); a1 = fmaf(x1.y, p.y, a1);
            a1 = fmaf(x1.z, p.z, a1); a1 = fmaf(x1.w, p.w, a1);
            a2 = fmaf(x2.x, p.x, a2); a2 = fmaf(x2.y, p.y, a2);
            a2 = fmaf(x2.z, p.z, a2); a2 = fmaf(x2.w, p.w, a2);
        }
        float* __restrict__ dst = out + (size_t)b * HSZ;
        dst[tid      ] = tanhf(a0 + out_b[tid      ]);
        dst[tid + 256] = tanhf(a1 + out_b[tid + 256]);
        dst[tid + 512] = tanhf(a2 + out_b[tid + 512]);
    }
}

// -----------------------------------------------------------------------------
// Launch.  inputs: 0 hidden | 1 verb_count | 2 subject_hidden | 3 align_w
//                  4 align_b | 5 out_w | 6 out_b
// subject_hidden / align_b / align_w[:H] cancel in softmax -> never read.
// d_ws is unused (pooled lives in LDS).
// -----------------------------------------------------------------------------
extern "C" void kernel_launch(void* const* d_in, const int* in_sizes, int n_in,
                              void* d_out, int out_size, void* d_ws, size_t ws_size,
                              hipStream_t stream) {
    const float* hidden     = (const float*)d_in[0];
    const int*   verb_count = (const int*)  d_in[1];
    const float* align_w    = (const float*)d_in[3];
    const float* out_w      = (const float*)d_in[5];
    const float* out_b      = (const float*)d_in[6];
    float*       out        = (float*)d_out;

    fused_pooler_kernel<<<dim3(BSZ), dim3(256), 0, stream>>>(
        hidden, verb_count, align_w, out_w, out_b, out);
}